// Round 1
// 221.723 us; speedup vs baseline: 1.0119x; 1.0119x over previous
//
#include <hip/hip_runtime.h>

// Problem constants: B=16, K=8, C=64, L=2048
#define BB 16
#define KK 8
#define CC 64
#define LL 2048

constexpr int CL = CC * LL;                            // 131072 elems per batch
constexpr int QUADS_PER_BATCH = CL / 4;                // 32768
constexpr int NBLOCKS = (BB * QUADS_PER_BATCH) / 256;  // 2048

#define SIG_OFF 0.11920292202211755f     // 1 - sigmoid(2) = sigmoid(-2)
#define LOG_EPS -16.11809565095832f      // logf(1e-7)

// k-stages in flight per wave. LDS = DEPTH * 3 arrays * 1024 floats * 4B = 48 KB
// -> 3 blocks/CU (144 KB of 160 KB), 12 waves/CU, each wave with 12 KB of
// global_load_lds DMA in flight (12 outstanding dwordx4 ops).
#define DEPTH 4

__device__ __forceinline__ float frcp(float x) { return __builtin_amdgcn_rcpf(x); }

__device__ __forceinline__ float get4(const float4& v, int e) {
    switch (e) {
        case 0: return v.x;
        case 1: return v.y;
        case 2: return v.z;
        default: return v.w;
    }
}

__device__ __forceinline__ void set4(float4& v, int e, float f) {
    switch (e) {
        case 0: v.x = f; break;
        case 1: v.y = f; break;
        case 2: v.z = f; break;
        default: v.w = f; break;
    }
}

// Async global->LDS DMA, 16B per lane. HW writes lane i at lds_base + i*16,
// so a wave-uniform base of &lds[slot][arr][wid*256] lands thread t's quad at
// &lds[slot][arr][t*4] — exactly where that thread reads it back. Wave-private:
// no cross-wave sharing, hence NO barriers anywhere in the pipeline.
__device__ __forceinline__ void glds16(const float* gsrc, const float* ldst) {
    __builtin_amdgcn_global_load_lds(
        (const __attribute__((address_space(1))) void*)gsrc,
        (__attribute__((address_space(3))) void*)ldst,
        16, 0, 0);
}

__global__ void init_sldj_kernel(const float* __restrict__ sldj_in,
                                 float* __restrict__ sldj_out) {
    int i = threadIdx.x;
    if (i < BB) sldj_out[i] = sldj_in[i];
}

__global__ __launch_bounds__(256) void coupling_kernel(
    const float* __restrict__ x,
    const float* __restrict__ a,
    const float* __restrict__ bv,
    const float* __restrict__ pi,
    const float* __restrict__ mu,
    const float* __restrict__ s,
    float* __restrict__ out,
    float* __restrict__ sldj_out) {

    __shared__ float lds[DEPTH][3][1024];   // 48 KB per-wave-partitioned FIFO

    const int tid = threadIdx.x;
    const int idx = blockIdx.x * 256 + tid;  // global quad index
    const int b   = idx >> 15;               // / 32768
    const int rem = idx & (QUADS_PER_BATCH - 1);
    const int base = b * CL + rem * 4;
    const int wid  = tid >> 6;

    // VMEM ops #1..#3 — pinned first so the manual vmcnt bookkeeping below holds.
    const float4 x4 = *(const float4*)(x + base);
    const float4 a4 = *(const float4*)(a + base);
    const float4 b4 = *(const float4*)(bv + base);
    __builtin_amdgcn_sched_barrier(0);

    const int kb0 = (b * KK) * CL + rem * 4;
    const float* pik = pi + kb0;
    const float* muk = mu + kb0;
    const float* svk = s  + kb0;

    // Prologue: fill the FIFO — stages 0..DEPTH-1, 3 DMAs each (ops #4..#15).
#pragma unroll
    for (int k = 0; k < DEPTH; ++k) {
        glds16(pik + k * CL, &lds[k][0][wid * 256]);
        glds16(muk + k * CL, &lds[k][1][wid * 256]);
        glds16(svk + k * CL, &lds[k][2][wid * 256]);
    }
    __builtin_amdgcn_sched_barrier(0);

    // Linear-domain mixture math (no per-k transcendental LSEs):
    //   Spi = sum_k e^{pi_k}
    //   Nc  = sum_k e^{pi_k} * sigmoid(z_k)            -> u   = Nc/Spi
    //   N1  = sum_k e^{pi_k} * (1 - sigmoid(z_k))      -> 1-u = N1/Spi
    //   Np  = sum_k e^{pi_k} * e^{-s_k} * sig*(1-sig)  -> pdf = Np/Spi
    float Spi[4] = {0.f, 0.f, 0.f, 0.f};
    float Nc[4]  = {0.f, 0.f, 0.f, 0.f};
    float N1[4]  = {0.f, 0.f, 0.f, 0.f};
    float Np[4]  = {0.f, 0.f, 0.f, 0.f};

#pragma unroll
    for (int k = 0; k < KK; ++k) {
        const int slot = k & (DEPTH - 1);

        // Counted wait for stage k only (ops #1..#(3+3(k+1)) done).
        // outstanding-allowed = 3*min(KK-1-k, DEPTH-1). Never vmcnt(0) until drain.
        if (k <= 4)      asm volatile("s_waitcnt vmcnt(9)" ::: "memory");
        else if (k == 5) asm volatile("s_waitcnt vmcnt(6)" ::: "memory");
        else if (k == 6) asm volatile("s_waitcnt vmcnt(3)" ::: "memory");
        else             asm volatile("s_waitcnt vmcnt(0)" ::: "memory");

        const float4 p4 = *(const float4*)&lds[slot][0][tid * 4];
        const float4 m4 = *(const float4*)&lds[slot][1][tid * 4];
        const float4 s4 = *(const float4*)&lds[slot][2][tid * 4];

        if (k < KK - DEPTH) {
            // WAR guard: the ds_reads above must have their data in VGPRs
            // before the DMA that overwrites this slot is issued. DMA writes
            // cannot land before their own issue, so lgkmcnt(0) suffices.
            asm volatile("s_waitcnt lgkmcnt(0)" ::: "memory");
            glds16(pik + (k + DEPTH) * CL, &lds[slot][0][wid * 256]);
            glds16(muk + (k + DEPTH) * CL, &lds[slot][1][wid * 256]);
            glds16(svk + (k + DEPTH) * CL, &lds[slot][2][wid * 256]);
        }

#pragma unroll
        for (int e = 0; e < 4; ++e) {
            const float p      = get4(p4, e);
            const float m      = get4(m4, e);
            const float sk     = get4(s4, e);
            const float invstd = __expf(-sk);
            const float z      = (get4(x4, e) - m) * invstd;

            // stable sigmoid via t = e^{-|z|}
            const float t  = __expf(-fabsf(z));
            const float r  = frcp(1.f + t);
            const float tr = t * r;
            const float sig  = (z >= 0.f) ? r  : tr;
            const float osig = (z >= 0.f) ? tr : r;

            const float ek = __expf(p);
            Spi[e] += ek;
            Nc[e]  += ek * sig;
            N1[e]  += ek * osig;
            Np[e]  += ek * invstd * sig * osig;
        }
    }

    float contrib = 0.f;
    float4 out4;

#pragma unroll
    for (int e = 0; e < 4; ++e) {
        const float lSpi = __logf(Spi[e]);
        const float lu   = fmaxf(__logf(Nc[e]) - lSpi, LOG_EPS);
        const float lomu = fmaxf(__logf(N1[e]) - lSpi, LOG_EPS);
        const float y        = lu - lomu;     // logit
        const float ldj_term = -lu - lomu;
        const float log_pdf  = __logf(Np[e]) - lSpi;

        // scale = sigmoid(a+2) + sigmoid(-2)
        const float ae = get4(a4, e) + 2.f;
        const float t2 = __expf(-fabsf(ae));
        const float r2 = frcp(1.f + t2);
        const float sc = ((ae >= 0.f) ? r2 : t2 * r2) + SIG_OFF;

        set4(out4, e, (y + get4(b4, e)) * sc);
        contrib += log_pdf + ldj_term + __logf(sc);
    }

    *(float4*)(out + base) = out4;

    // ---- block reduction, one atomicAdd per block (block is within batch b) ----
#pragma unroll
    for (int off = 32; off > 0; off >>= 1)
        contrib += __shfl_down(contrib, off, 64);

    __shared__ float wsum[4];
    const int lane = tid & 63;
    if (lane == 0) wsum[wid] = contrib;
    __syncthreads();
    if (tid == 0) {
        atomicAdd(&sldj_out[b], wsum[0] + wsum[1] + wsum[2] + wsum[3]);
    }
}

extern "C" void kernel_launch(void* const* d_in, const int* in_sizes, int n_in,
                              void* d_out, int out_size, void* d_ws, size_t ws_size,
                              hipStream_t stream) {
    const float* x    = (const float*)d_in[0];
    const float* a    = (const float*)d_in[1];
    const float* bv   = (const float*)d_in[2];
    const float* pi   = (const float*)d_in[3];
    const float* mu   = (const float*)d_in[4];
    const float* s    = (const float*)d_in[5];
    const float* sldj = (const float*)d_in[6];

    float* out      = (float*)d_out;
    float* sldj_out = out + (size_t)BB * CL;  // outputs concat: out, then sldj

    init_sldj_kernel<<<1, 64, 0, stream>>>(sldj, sldj_out);
    coupling_kernel<<<NBLOCKS, 256, 0, stream>>>(x, a, bv, pi, mu, s, out, sldj_out);
}